// Round 7
// baseline (1339.384 us; speedup 1.0000x reference)
//
#include <hip/hip_runtime.h>
#include <math.h>

#define B_ 8
#define T_ 512
#define FEAT_ 128
#define TP 256          // T' after frontend
#define DM 128          // d_model
#define DI 256          // d_inner
#define DS 16           // d_state
#define DTR 8
#define NL 10

__device__ __forceinline__ float fsilu(float x){ return x / (1.f + __expf(-x)); }
__device__ __forceinline__ float fsoftplus(float x){ return (x > 20.f) ? x : log1pf(__expf(x)); }

// ---------- transpose x [8,512,128] -> xT [8,128,512]
__global__ void k_transpose_x(const float* __restrict__ x, float* __restrict__ xT){
  int idx = blockIdx.x*256 + threadIdx.x;
  if(idx >= B_*FEAT_*T_) return;
  int t = idx % T_; int f = (idx/T_) % FEAT_; int b = idx/(T_*FEAT_);
  xT[idx] = x[((size_t)b*T_ + t)*FEAT_ + f];
}

// ---------- all 4 conv-weight transposes in one launch.
// out layout: [ci][slot][72] where slot = co/8, within = (co%8)*9 + k
__device__ __forceinline__ void wt_one(const float* __restrict__ w, float* __restrict__ o,
                                       int idx, int CO, int CIN){
  int k = idx % 9; int ci = (idx/9) % CIN; int co = idx/(9*CIN);
  o[((size_t)(ci*(CO>>3) + (co>>3)))*72 + (co&7)*9 + k] = w[idx];
}
__global__ void k_wt_all(const float* __restrict__ w1, const float* __restrict__ w2,
                         const float* __restrict__ w3, const float* __restrict__ w4,
                         float* __restrict__ o1, float* __restrict__ o2,
                         float* __restrict__ o3, float* __restrict__ o4){
  int idx = blockIdx.x*256 + threadIdx.x;
  if(idx < 288){ wt_one(w1, o1, idx, 32, 1); return; }
  idx -= 288;
  if(idx < 9216){ wt_one(w2, o2, idx, 32, 32); return; }
  idx -= 9216;
  if(idx < 18432){ wt_one(w3, o3, idx, 64, 32); return; }
  idx -= 18432;
  if(idx < 36864){ wt_one(w4, o4, idx, 64, 64); return; }
}

// ---------- tiled direct 3x3 SAME conv + folded BN + SiLU (v5 lane map).
template<int CIN, int CO, int CPW, int CIG, int COG>
__global__ __launch_bounds__(256) void k_conv_t4(const float* __restrict__ in,
     const float* __restrict__ wt, const float* __restrict__ cb,
     const float* __restrict__ bs, const float* __restrict__ bb,
     float* __restrict__ out, int H, int W){
  constexpr int NS = CO/CPW;
  __shared__ __align__(16) float tile[CIG*360];   // [CIG][18][20]
  int tid = threadIdx.x;
  int lane = tid & 63;
  int wav = __builtin_amdgcn_readfirstlane(tid >> 6);
  int wpr = W >> 4, hpr = H >> 4;
  int idx = blockIdx.x;
  int cog = idx % COG; idx /= COG;
  int tj = idx % wpr; idx /= wpr;
  int ti = idx % hpr; int b = idx / hpr;
  int i0 = ti*16, j0 = tj*16;
  int r = lane & 15, cg = lane >> 4;
  int wslot = cog*4 + wav;
  const float* wbase = wt + (size_t)wslot*72;
  float acc[CPW][4] = {};
  for(int cig = 0; cig < CIN; cig += CIG){
    __syncthreads();
    for(int u = tid; u < CIG*324; u += 256){
      int ci = u / 324; int rem = u - ci*324; int rr = rem / 18; int cc = rem - rr*18;
      int gi = i0 - 1 + rr, gj = j0 - 1 + cc;
      float v = 0.f;
      if(gi >= 0 && gi < H && gj >= 0 && gj < W)
        v = in[((size_t)(b*CIN + cig + ci)*H + gi)*W + gj];
      tile[ci*360 + rr*20 + cc] = v;
    }
    __syncthreads();
    for(int ci = 0; ci < CIG; ci++){
      const float4* wp4 = (const float4*)(wbase + (size_t)(cig+ci)*(NS*72));
      float4 w4q[18];
      #pragma unroll
      for(int q=0;q<18;q++) w4q[q] = wp4[q];
      const float* wf = (const float*)w4q;
      #pragma unroll
      for(int kh=0;kh<3;kh++){
        float4 a = *(const float4*)&tile[ci*360 + (r+kh)*20 + cg*4];
        float4 bv = *(const float4*)&tile[ci*360 + (r+kh)*20 + cg*4 + 4];
        float v[6] = {a.x,a.y,a.z,a.w,bv.x,bv.y};
        #pragma unroll
        for(int co=0;co<CPW;co++){
          #pragma unroll
          for(int kw=0;kw<3;kw++){
            float wv = wf[co*9 + kh*3 + kw];
            #pragma unroll
            for(int u2=0;u2<4;u2++)
              acc[co][u2] = fmaf(wv, v[kw+u2], acc[co][u2]);
          }
        }
      }
    }
  }
  int i = i0 + r;
  #pragma unroll
  for(int co=0; co<CPW; co++){
    int c = cog*(4*CPW) + wav*CPW + co;
    float s = bs[c], bias = cb[c]*s + bb[c];
    float4 o;
    o.x = fsilu(acc[co][0]*s + bias);
    o.y = fsilu(acc[co][1]*s + bias);
    o.z = fsilu(acc[co][2]*s + bias);
    o.w = fsilu(acc[co][3]*s + bias);
    *(float4*)&out[((size_t)(b*CO + c)*H + i)*W + j0 + cg*4] = o;
  }
}

// ---------- 2x2 max pool stride 2
__global__ void k_pool2x2(const float* __restrict__ in, float* __restrict__ out,
                          int C, int Hi, int Wi){
  int Ho = Hi>>1, Wo = Wi>>1;
  int total = B_*C*Ho*Wo;
  int idx = blockIdx.x*256 + threadIdx.x;
  if(idx >= total) return;
  int j = idx % Wo; int i = (idx/Wo)%Ho; int c = (idx/(Wo*Ho))%C; int b = idx/(Wo*Ho*C);
  const float* p = in + (((size_t)(b*C+c)*Hi + 2*i)*Wi + 2*j);
  out[idx] = fmaxf(fmaxf(p[0], p[1]), fmaxf(p[Wi], p[Wi+1]));
}

// ---------- fused (2,1)-maxpool + proj GEMM, split-K x8.
__global__ __launch_bounds__(256) void k_proj(const float* __restrict__ R0,
    const float* __restrict__ W, float* __restrict__ pbuf){
  __shared__ __align__(16) float As[16][33];
  __shared__ __align__(16) float Ws[16][68];
  int tid = threadIdx.x;
  int n0 = blockIdx.x*64, m0 = blockIdx.y*32;
  int kc = blockIdx.z;
  int b = m0 >> 8;
  int t_base = m0 & 255;
  int tx = tid&15, ty = tid>>4;
  float acc[2][4] = {};
  for(int k0=0; k0<256; k0+=16){
    int kg0 = kc*256 + k0;
    if(tid < 128){
      int row = tid>>2, cq = (tid&3)*4;
      #pragma unroll
      for(int c2=0;c2<4;c2++){
        int k = kg0 + cq + c2;
        int c = k>>5, hh = k&31;
        const float* p = R0 + (((size_t)(b*64+c)*64 + 2*hh)*256 + t_base + row);
        As[cq+c2][row] = fmaxf(p[0], p[256]);
      }
    } else {
      int u = tid - 128; int n = u>>1, cq = (u&1)*8;
      const float* wp = W + (size_t)(n0+n)*2048 + kg0 + cq;
      float4 v0 = *(const float4*)wp, v1 = *(const float4*)(wp+4);
      Ws[cq+0][n]=v0.x; Ws[cq+1][n]=v0.y; Ws[cq+2][n]=v0.z; Ws[cq+3][n]=v0.w;
      Ws[cq+4][n]=v1.x; Ws[cq+5][n]=v1.y; Ws[cq+6][n]=v1.z; Ws[cq+7][n]=v1.w;
    }
    __syncthreads();
    #pragma unroll
    for(int kk=0;kk<16;kk++){
      float a0 = As[kk][ty*2+0];
      float a1 = As[kk][ty*2+1];
      float4 w4 = *(const float4*)&Ws[kk][tx*4];
      float wv4[4] = {w4.x,w4.y,w4.z,w4.w};
      #pragma unroll
      for(int j=0;j<4;j++){
        acc[0][j] = fmaf(a0, wv4[j], acc[0][j]);
        acc[1][j] = fmaf(a1, wv4[j], acc[1][j]);
      }
    }
    __syncthreads();
  }
  float* pb = pbuf + (size_t)kc*2048*DM;
  #pragma unroll
  for(int iu=0;iu<2;iu++){
    int m = m0 + ty*2 + iu;
    #pragma unroll
    for(int j=0;j<4;j++){
      int n = n0 + tx*4 + j;
      pb[(size_t)m*DM + n] = acc[iu][j];
    }
  }
}

// ---------- reduce 8 split-K partials + bias + LN + SiLU -> hbuf. 1 wave/row.
__global__ void k_lnp(const float* __restrict__ pbuf, const float* __restrict__ bias,
                      const float* __restrict__ g, const float* __restrict__ b,
                      float* __restrict__ out){
  int row = blockIdx.x;
  int t = threadIdx.x; // 64
  float v0 = bias[t], v1 = bias[t+64];
  #pragma unroll
  for(int kc=0;kc<8;kc++){
    const float* p = pbuf + ((size_t)kc*2048 + row)*DM;
    v0 += p[t]; v1 += p[t+64];
  }
  float s = v0 + v1;
  #pragma unroll
  for(int m=32;m>=1;m>>=1) s += __shfl_xor(s, m);
  float mean = s * (1.f/128.f);
  float e0 = v0-mean, e1 = v1-mean;
  float q = e0*e0 + e1*e1;
  #pragma unroll
  for(int m=32;m>=1;m>>=1) q += __shfl_xor(q, m);
  float inv = rsqrtf(q*(1.f/128.f) + 1e-5f);
  float o0 = fsilu(e0*inv*g[t] + b[t]);
  float o1 = fsilu(e1*inv*g[t+64] + b[t+64]);
  float* po = out + (size_t)row*DM;
  po[t] = o0; po[t+64] = o1;
}

// ---------- fused mamba-input: LN -> xz GEMM -> dwconv+SiLU -> dbc GEMM -> dt.
// 8 rows/block (+3 halo rows recomputed), grid 256, 256 thr, 5 phases.
__global__ __launch_bounds__(256) void k_min(const float* __restrict__ hb,
    const float* __restrict__ g, const float* __restrict__ bb,
    const float* __restrict__ W,       // in_w [512][128]
    const float* __restrict__ cw, const float* __restrict__ cb,
    const float* __restrict__ xpw, const float* __restrict__ dtw,
    const float* __restrict__ dtb_,
    float* __restrict__ zb, float* __restrict__ xc_g,
    float* __restrict__ dbc_g, float* __restrict__ dt_g){
  __shared__ __align__(16) float lns[11][132];
  __shared__ __align__(16) float xms[11][260];
  __shared__ __align__(16) float xcs[8][260];
  __shared__ float Wp[64][41];
  __shared__ float dtin[8][9];
  int tid = threadIdx.x;
  int row0 = blockIdx.x*8; int b = row0 >> 8; int t0 = row0 & 255;
  // ---- A: load 11 rows (3 halo + 8 own), zero-pad t<0
  for(int u=tid; u<11*128; u+=256){
    int r = u>>7, col = u&127;
    int t = t0 - 3 + r;
    lns[r][col] = (t >= 0) ? hb[((size_t)(b*TP)+t)*DM + col] : 0.f;
  }
  __syncthreads();
  // ---- LN in place (wave w handles rows w, w+4, w+8)
  {
    int lane = tid & 63, wv = tid >> 6;
    for(int r = wv; r < 11; r += 4){
      float v0 = lns[r][lane], v1 = lns[r][lane+64];
      float s = v0+v1;
      #pragma unroll
      for(int mm=32;mm>=1;mm>>=1) s += __shfl_xor(s,mm);
      float mean = s*(1.f/128.f);
      float e0 = v0-mean, e1 = v1-mean;
      float q = e0*e0+e1*e1;
      #pragma unroll
      for(int mm=32;mm>=1;mm>>=1) q += __shfl_xor(q,mm);
      float inv = rsqrtf(q*(1.f/128.f)+1e-5f);
      lns[r][lane]    = e0*inv*g[lane] + bb[lane];
      lns[r][lane+64] = e1*inv*g[lane+64] + bb[lane+64];
    }
  }
  __syncthreads();
  // ---- B: xz GEMM. thread owns 1 col (of 256) per pass; pass0=xm, pass1=z.
  {
    int c2 = tid & 63, chq = tid >> 6;
    int colb = chq*64 + c2;
    #pragma unroll
    for(int pass=0; pass<2; pass++){
      const float* wp = W + (size_t)(pass*256 + colb)*DM;
      float acc[11];
      #pragma unroll
      for(int r=0;r<11;r++) acc[r]=0.f;
      for(int kb=0; kb<128; kb+=32){
        float wreg[32];
        #pragma unroll
        for(int q=0;q<8;q++){
          float4 w4 = *(const float4*)(wp + kb + q*4);
          wreg[q*4]=w4.x; wreg[q*4+1]=w4.y; wreg[q*4+2]=w4.z; wreg[q*4+3]=w4.w;
        }
        #pragma unroll
        for(int r=0;r<11;r++){
          #pragma unroll
          for(int q=0;q<8;q++){
            float4 a4 = *(const float4*)&lns[r][kb+q*4];
            acc[r] = fmaf(a4.x, wreg[q*4+0], acc[r]);
            acc[r] = fmaf(a4.y, wreg[q*4+1], acc[r]);
            acc[r] = fmaf(a4.z, wreg[q*4+2], acc[r]);
            acc[r] = fmaf(a4.w, wreg[q*4+3], acc[r]);
          }
        }
      }
      if(pass==0){
        #pragma unroll
        for(int r=0;r<11;r++)
          xms[r][colb] = (t0-3+r >= 0) ? acc[r] : 0.f;
      } else {
        #pragma unroll
        for(int r=3;r<11;r++)
          zb[((size_t)(row0 + r-3))*DI + colb] = acc[r];
      }
    }
  }
  __syncthreads();
  // ---- C: causal dwconv(4) + SiLU
  {
    int d = tid;
    float4 cw4 = *(const float4*)&cw[d*4];
    float cbv = cb[d];
    #pragma unroll
    for(int r2=0;r2<8;r2++){
      float a = cbv;
      a = fmaf(cw4.x, xms[r2+0][d], a);
      a = fmaf(cw4.y, xms[r2+1][d], a);
      a = fmaf(cw4.z, xms[r2+2][d], a);
      a = fmaf(cw4.w, xms[r2+3][d], a);
      float v = fsilu(a);
      xcs[r2][d] = v;
      xc_g[((size_t)(row0+r2))*DI + d] = v;
    }
  }
  // ---- D: dbc GEMM (8 rows x 40 cols, K=256), Wp staged per 64-k chunk
  {
    int row = tid>>5, cg = tid&31;
    float a0 = 0.f, a1 = 0.f;
    for(int ch2=0; ch2<4; ch2++){
      __syncthreads();
      for(int u=tid; u<40*64; u+=256){
        int nn = u>>6, dk = u&63;
        Wp[dk][nn] = xpw[(size_t)nn*DI + ch2*64 + dk];
      }
      __syncthreads();
      #pragma unroll 8
      for(int dk=0; dk<64; dk++){
        float a = xcs[row][ch2*64+dk];
        a0 = fmaf(a, Wp[dk][cg], a0);
        if(cg < 8) a1 = fmaf(a, Wp[dk][cg+32], a1);
      }
    }
    if(cg < 8){
      dtin[row][cg] = a0;
      dbc_g[((size_t)(row0+row))*40 + 32 + cg] = a1;
    } else {
      dbc_g[((size_t)(row0+row))*40 + cg] = a0;
    }
  }
  __syncthreads();
  // ---- E: dt = softplus(dtin @ dtw^T + dtb)
  {
    int d = tid;
    float bias = dtb_[d];
    float4 wa = *(const float4*)&dtw[d*8];
    float4 wb = *(const float4*)&dtw[d*8+4];
    #pragma unroll
    for(int r2=0;r2<8;r2++){
      float a = bias;
      a = fmaf(dtin[r2][0], wa.x, a); a = fmaf(dtin[r2][1], wa.y, a);
      a = fmaf(dtin[r2][2], wa.z, a); a = fmaf(dtin[r2][3], wa.w, a);
      a = fmaf(dtin[r2][4], wb.x, a); a = fmaf(dtin[r2][5], wb.y, a);
      a = fmaf(dtin[r2][6], wb.z, a); a = fmaf(dtin[r2][7], wb.w, a);
      dt_g[((size_t)(row0+r2))*DI + d] = fsoftplus(a);
    }
  }
}

// ---------- chunked selective scan v3: 8 chunks of 32, block 1024 thr.
__global__ __launch_bounds__(1024) void k_scan3(const float* __restrict__ dtb,
      const float* __restrict__ xc, const float* __restrict__ zb,
      const float* __restrict__ dbc, const float* __restrict__ A_log,
      const float* __restrict__ Dp, float* __restrict__ y){
  __shared__ float dt_s[TP][8], xc_s[TP][8];
  __shared__ float Bs[TP][16], Cs[TP][16];
  __shared__ float Eb[8][128], Pb[8][128];
  int tid = threadIdx.x;
  int c = tid >> 7, gl = (tid >> 4) & 7, n = tid & 15;
  int dblk = blockIdx.x & 31, b = blockIdx.x >> 5;
  int d0 = dblk*8;
  size_t rbase = (size_t)b*TP;
  for(int u=tid; u<TP*8; u+=1024){
    int tt = u>>3, gg = u&7;
    size_t r = rbase + tt;
    dt_s[tt][gg] = dtb[r*DI + d0 + gg];
    xc_s[tt][gg] = xc [r*DI + d0 + gg];
  }
  for(int u=tid; u<TP*16; u+=1024){
    int tt = u>>4, nn = u&15;
    size_t r = rbase + tt;
    Bs[tt][nn] = dbc[r*40 + 8  + nn];
    Cs[tt][nn] = dbc[r*40 + 24 + nn];
  }
  __syncthreads();
  int d = d0 + gl;
  float An = -__expf(A_log[d*DS + n]);
  float h = 0.f, dtsum = 0.f;
  int tA = c*32;
  float yloc[32], ev[32];
  #pragma unroll
  for(int i=0;i<32;i++){
    int t = tA + i;
    float dtv = dt_s[t][gl];
    dtsum += dtv;
    float e = __expf(dtv*An);
    ev[i] = e;
    h = fmaf(e, h, dtv*xc_s[t][gl]*Bs[t][n]);
    float p = h*Cs[t][n];
    p += __shfl_xor(p,1); p += __shfl_xor(p,2);
    p += __shfl_xor(p,4); p += __shfl_xor(p,8);
    yloc[i] = p;
  }
  Eb[c][gl*16+n] = h;
  Pb[c][gl*16+n] = __expf(An*dtsum);
  __syncthreads();
  float g = 0.f;
  for(int cp=0; cp<c; cp++)
    g = fmaf(Pb[cp][gl*16+n], g, Eb[cp][gl*16+n]);
  float Dpd = Dp[d];
  #pragma unroll
  for(int i=0;i<32;i++){
    int t = tA + i;
    g *= ev[i];
    float p = g*Cs[t][n];
    p += __shfl_xor(p,1); p += __shfl_xor(p,2);
    p += __shfl_xor(p,4); p += __shfl_xor(p,8);
    if(n==0){
      float zv = zb[(rbase+t)*DI + d];
      float xcv = xc_s[t][gl];
      y[(rbase+t)*DI + d] = (yloc[i] + p + Dpd*xcv) * fsilu(zv);
    }
  }
}

// ---------- out-proj GEMM + residual, 16-row tiles: grid (2, 128).
__global__ __launch_bounds__(256) void k_out16(const float* __restrict__ A,
    const float* __restrict__ W, float* __restrict__ C){
  __shared__ float As[16][17];
  __shared__ __align__(16) float Ws[16][68];
  int tid = threadIdx.x;
  int n0 = blockIdx.x*64, m0 = blockIdx.y*16;
  int tx = tid&15, ty = tid>>4;
  float acc[4] = {};
  for(int k0=0;k0<256;k0+=16){
    {
      int row = tid>>4, kk = tid&15;
      As[kk][row] = A[(size_t)(m0+row)*DI + k0 + kk];
    }
    {
      int n = tid>>2, cq = (tid&3)*4;
      float4 v = *(const float4*)(W + (size_t)(n0+n)*DI + k0 + cq);
      Ws[cq+0][n]=v.x; Ws[cq+1][n]=v.y; Ws[cq+2][n]=v.z; Ws[cq+3][n]=v.w;
    }
    __syncthreads();
    #pragma unroll
    for(int kk=0;kk<16;kk++){
      float a0 = As[kk][ty];
      float4 w4 = *(const float4*)&Ws[kk][tx*4];
      acc[0] = fmaf(a0, w4.x, acc[0]);
      acc[1] = fmaf(a0, w4.y, acc[1]);
      acc[2] = fmaf(a0, w4.z, acc[2]);
      acc[3] = fmaf(a0, w4.w, acc[3]);
    }
    __syncthreads();
  }
  int m = m0 + ty;
  float* cp = &C[(size_t)m*DM + n0 + tx*4];
  cp[0] += acc[0]; cp[1] += acc[1]; cp[2] += acc[2]; cp[3] += acc[3];
}

// ---------- fused pre-LN + masked mean pool + classifier. grid 8, block 256.
__global__ __launch_bounds__(256) void k_head2(const float* __restrict__ h,
    const int* __restrict__ lengths, const float* __restrict__ g,
    const float* __restrict__ bv, const float* __restrict__ w1,
    const float* __restrict__ b1, const float* __restrict__ w2,
    const float* __restrict__ b2, float* __restrict__ out){
  __shared__ float pp[4][128];
  __shared__ float pooled[DM];
  __shared__ float cbuf[64];
  int b = blockIdx.x, tid = threadIdx.x;
  int lane = tid & 63, wv = tid >> 6;
  int tl = lengths[b] >> 1; if(tl < 1) tl = 1;
  float p0 = 0.f, p1 = 0.f;
  for(int t = wv; t < tl; t += 4){
    const float* row = h + ((size_t)(b*TP)+t)*DM;
    float v0 = row[lane], v1 = row[lane+64];
    float s = v0+v1;
    #pragma unroll
    for(int mm=32;mm>=1;mm>>=1) s += __shfl_xor(s,mm);
    float mean = s*(1.f/128.f);
    float e0 = v0-mean, e1 = v1-mean;
    float q = e0*e0+e1*e1;
    #pragma unroll
    for(int mm=32;mm>=1;mm>>=1) q += __shfl_xor(q,mm);
    float inv = rsqrtf(q*(1.f/128.f)+1e-5f);
    p0 += e0*inv*g[lane] + bv[lane];
    p1 += e1*inv*g[lane+64] + bv[lane+64];
  }
  pp[wv][lane] = p0; pp[wv][lane+64] = p1;
  __syncthreads();
  if(tid < 128)
    pooled[tid] = (pp[0][tid]+pp[1][tid]+pp[2][tid]+pp[3][tid]) / (float)tl;
  __syncthreads();
  if(tid < 64){
    float a = b1[tid];
    const float* wp = w1 + tid*DM;
    for(int k=0;k<DM;k++) a = fmaf(pooled[k], wp[k], a);
    cbuf[tid] = fsilu(a);
  }
  __syncthreads();
  if(tid < 35){
    float a = b2[tid];
    const float* wp = w2 + tid*64;
    for(int k=0;k<64;k++) a = fmaf(cbuf[k], wp[k], a);
    out[b*35+tid] = a;
  }
}

extern "C" void kernel_launch(void* const* d_in, const int* in_sizes, int n_in,
                              void* d_out, int out_size, void* d_ws, size_t ws_size,
                              hipStream_t stream){
  (void)in_sizes; (void)n_in; (void)out_size; (void)ws_size;
  const float* x        = (const float*)d_in[0];
  const int*   lengths  = (const int*)  d_in[1];
  const float* conv_w1  = (const float*)d_in[2];  const float* conv_b1 = (const float*)d_in[3];
  const float* bn1_s    = (const float*)d_in[4];  const float* bn1_b   = (const float*)d_in[5];
  const float* conv_w2  = (const float*)d_in[6];  const float* conv_b2 = (const float*)d_in[7];
  const float* bn2_s    = (const float*)d_in[8];  const float* bn2_b   = (const float*)d_in[9];
  const float* conv_w3  = (const float*)d_in[10]; const float* conv_b3 = (const float*)d_in[11];
  const float* bn3_s    = (const float*)d_in[12]; const float* bn3_b   = (const float*)d_in[13];
  const float* conv_w4  = (const float*)d_in[14]; const float* conv_b4 = (const float*)d_in[15];
  const float* bn4_s    = (const float*)d_in[16]; const float* bn4_b   = (const float*)d_in[17];
  const float* proj_w   = (const float*)d_in[18]; const float* proj_b  = (const float*)d_in[19];
  const float* proj_ln_s= (const float*)d_in[20]; const float* proj_ln_b=(const float*)d_in[21];
  const float* blk_ln_s = (const float*)d_in[22]; const float* blk_ln_b =(const float*)d_in[23];
  const float* in_w     = (const float*)d_in[24];
  const float* cw       = (const float*)d_in[25]; const float* cbv     = (const float*)d_in[26];
  const float* xp_w     = (const float*)d_in[27];
  const float* dt_w     = (const float*)d_in[28]; const float* dt_b    = (const float*)d_in[29];
  const float* A_log    = (const float*)d_in[30]; const float* Dp      = (const float*)d_in[31];
  const float* out_w    = (const float*)d_in[32];
  const float* pre_ln_s = (const float*)d_in[33]; const float* pre_ln_b= (const float*)d_in[34];
  const float* cls_w1   = (const float*)d_in[35]; const float* cls_b1  = (const float*)d_in[36];
  const float* cls_w2   = (const float*)d_in[37]; const float* cls_b2  = (const float*)d_in[38];

  float* ws   = (float*)d_ws;
  float* R0   = ws;                  // 16,777,216 floats (conv ping)
  float* R1   = R0 + 16777216;       // 16,777,216 floats (conv pong / proj partials)
  float* xT   = R1 + 16777216;       // 524,288
  float* hbuf = xT + 524288;         // 262,144
  float* lnb  = hbuf + 262144;       // 262,144 (spare)
  float* zb   = lnb + 262144;        // 524,288 (z buffer, [2048][256])
  float* xcb  = zb + 1048576;        // 524,288
  float* dbcb = xcb + 524288;        // 81,920
  float* dtbb = dbcb + 81920;        // 524,288
  float* yb   = dtbb + 524288;       // 524,288
  float* wt1  = yb + 524288;         // 288
  float* wt2  = wt1 + 288;           // 9,216
  float* wt3  = wt2 + 9216;          // 18,432
  float* wt4  = wt3 + 18432;         // 36,864

  // ---- weight transposes (one launch)
  k_wt_all<<<254, 256, 0, stream>>>(conv_w1, conv_w2, conv_w3, conv_w4, wt1, wt2, wt3, wt4);

  // ---- frontend
  k_transpose_x<<<2048, 256, 0, stream>>>(x, xT);
  k_conv_t4<1,32,8,1,1><<<8*8*32, 256, 0, stream>>>(xT, wt1, conv_b1, bn1_s, bn1_b, R0, 128, 512);
  k_conv_t4<32,32,8,8,1><<<8*8*32, 256, 0, stream>>>(R0, wt2, conv_b2, bn2_s, bn2_b, R1, 128, 512);
  k_pool2x2<<<(8*32*64*256)/256, 256, 0, stream>>>(R1, R0, 32, 128, 512);
  k_conv_t4<32,64,8,8,2><<<8*4*16*2, 256, 0, stream>>>(R0, wt3, conv_b3, bn3_s, bn3_b, R1, 64, 256);
  k_conv_t4<64,64,8,8,2><<<8*4*16*2, 256, 0, stream>>>(R1, wt4, conv_b4, bn4_s, bn4_b, R0, 64, 256);

  // ---- fused pool(2,1) + projection GEMM (split-K x8) -> partials in R1
  {
    dim3 gd(2, 64, 8);
    k_proj<<<gd, 256, 0, stream>>>(R0, proj_w, R1);
  }
  k_lnp<<<2048, 64, 0, stream>>>(R1, proj_b, proj_ln_s, proj_ln_b, hbuf);

  // ---- mamba layers: 3 dispatches each
  for(int i=0;i<NL;i++){
    k_min<<<256, 256, 0, stream>>>(hbuf, blk_ln_s + i*DM, blk_ln_b + i*DM,
                                   in_w + (size_t)i*512*DM,
                                   cw + (size_t)i*DI*4, cbv + i*DI,
                                   xp_w + (size_t)i*40*DI, dt_w + (size_t)i*DI*DTR,
                                   dt_b + i*DI, zb, xcb, dbcb, dtbb);
    k_scan3<<<256, 1024, 0, stream>>>(dtbb, xcb, zb, dbcb, A_log + (size_t)i*DI*DS, Dp + i*DI, yb);
    { dim3 gd(2, 128);
      k_out16<<<gd, 256, 0, stream>>>(yb, out_w + (size_t)i*DM*DI, hbuf); }
  }

  // ---- head (pre-LN fused)
  k_head2<<<8, 256, 0, stream>>>(hbuf, lengths, pre_ln_s, pre_ln_b,
                                 cls_w1, cls_b1, cls_w2, cls_b2, (float*)d_out);
}